// Round 23
// baseline (133.389 us; speedup 1.0000x reference)
//
#include <hip/hip_runtime.h>
#include <math.h>

typedef __attribute__((ext_vector_type(8))) short short8;
typedef __attribute__((ext_vector_type(4))) float f32x4;
typedef __attribute__((ext_vector_type(2))) unsigned int u32x2;

#define AS1 __attribute__((address_space(1)))
#define AS3 __attribute__((address_space(3)))

__device__ __forceinline__ float b2f(short s){
  return __uint_as_float(((unsigned int)(unsigned short)s) << 16);
}
__device__ __forceinline__ short f2b(float f){
  unsigned int u = __float_as_uint(f);
  u = (u + 0x7fffu + ((u >> 16) & 1u)) >> 16;
  return (short)u;
}
__device__ __forceinline__ unsigned pk2(float lo, float hi){
  return ((unsigned)(unsigned short)f2b(hi) << 16) | (unsigned)(unsigned short)f2b(lo);
}
__device__ __forceinline__ float ulo(unsigned u){ return __uint_as_float(u << 16); }
__device__ __forceinline__ float uhi(unsigned u){ return __uint_as_float(u & 0xffff0000u); }

// ---------------- weight f32 -> bf16 ----------------
// dst: row-major (6 mats). dstS: stage-order [s][row][g][8], slots
// {0:W_o, 1:W_m1, 2:W_m2, 3:W_q}.
__global__ __launch_bounds__(256) void cvt_w(
    const float* __restrict__ s0, const float* __restrict__ s1,
    const float* __restrict__ s2, const float* __restrict__ s3,
    const float* __restrict__ s4, const float* __restrict__ s5,
    short* __restrict__ dst, short* __restrict__ dstS)
{
  const float* srcs[6] = {s0, s1, s2, s3, s4, s5};
  int i = blockIdx.x * 256 + threadIdx.x;       // 6*65536 total
  int mat = i >> 16, rc = i & 65535;
  short v = f2b(srcs[mat][rc]);
  dst[i] = v;
  int slot = (mat >= 3) ? (mat - 3) : (mat == 0 ? 3 : -1);
  if (slot >= 0){
    int row = rc >> 8, col = rc & 255;
    int d2 = slot * 65536 + ((col >> 5) << 13) + (row << 5)
           + (((col >> 3) & 3) << 3) + (col & 7);
    dstS[d2] = v;
  }
}

// -------- fused K+V projection: LN(cluster) once, two k-loops, frag outs ----
__global__ __launch_bounds__(256, 2) void kv_k(
    const float* __restrict__ cluster,
    const short* __restrict__ Wk, const short* __restrict__ Wv,
    const float* __restrict__ b_k, const float* __restrict__ b_v,
    const float* __restrict__ lng, const float* __restrict__ lnb,
    short* __restrict__ kfrag, short* __restrict__ vfrag)
{
  __shared__ short As[64][264];
  __shared__ short Ws[2][256][40];
  const int tid = threadIdx.x;
  const int m0 = blockIdx.x << 6;
  const int w = tid >> 6, lane = tid & 63;
  const int l15 = lane & 15, g = lane >> 4;

  // ---- LN prologue (reads cluster once) ----
  {
    const int row = tid >> 2, c0 = (tid & 3) << 6;
    float vv[64];
    const float* src = &cluster[(size_t)(m0 + row) * 256 + c0];
    #pragma unroll
    for (int i = 0; i < 16; ++i) *(f32x4*)&vv[4 * i] = *(const f32x4*)&src[4 * i];
    float s1 = 0.f, s2 = 0.f;
    #pragma unroll
    for (int i = 0; i < 64; ++i){ s1 += vv[i]; s2 += vv[i] * vv[i]; }
    s1 += __shfl_xor(s1, 1); s2 += __shfl_xor(s2, 1);
    s1 += __shfl_xor(s1, 2); s2 += __shfl_xor(s2, 2);
    const float mu = s1 * 0.00390625f;
    const float rs = rsqrtf(s2 * 0.00390625f - mu * mu + 1e-5f);
    #pragma unroll
    for (int i = 0; i < 8; ++i){
      f32x4 gv0 = *(const f32x4*)&lng[c0 + 8 * i];
      f32x4 gv1 = *(const f32x4*)&lng[c0 + 8 * i + 4];
      f32x4 bv0 = *(const f32x4*)&lnb[c0 + 8 * i];
      f32x4 bv1 = *(const f32x4*)&lnb[c0 + 8 * i + 4];
      short8 o;
      #pragma unroll
      for (int j = 0; j < 4; ++j) o[j] = f2b((vv[8 * i + j] - mu) * rs * gv0[j] + bv0[j]);
      #pragma unroll
      for (int j = 0; j < 4; ++j) o[4 + j] = f2b((vv[8 * i + 4 + j] - mu) * rs * gv1[j] + bv1[j]);
      *(short8*)&As[row][c0 + 8 * i] = o;
    }
  }

  f32x4 acc[16];
  const int row_l = (w << 4) + (g << 2);

#define KV_LOOP(WMAT)                                                                 \
  do{                                                                                 \
    _Pragma("unroll")                                                                 \
    for (int it = 0; it < 4; ++it){                                                   \
      int row = (it << 6) + (tid >> 2), c = (tid & 3) << 3;                           \
      *(short8*)&Ws[0][row][c] = *(const short8*)&(WMAT)[(size_t)row * 256 + c];      \
    }                                                                                 \
    __syncthreads();                                                                  \
    _Pragma("unroll")                                                                 \
    for (int nt = 0; nt < 16; ++nt) acc[nt] = (f32x4){0.f, 0.f, 0.f, 0.f};            \
    int cur = 0;                                                                      \
    for (int s = 0; s < 8; ++s){                                                      \
      const int k0 = s << 5;                                                          \
      short8 wreg[4];                                                                 \
      if (s < 7){                                                                     \
        _Pragma("unroll")                                                             \
        for (int it = 0; it < 4; ++it)                                                \
          wreg[it] = *(const short8*)&(WMAT)[(size_t)((it << 6) + (tid >> 2)) * 256 + k0 + 32 + ((tid & 3) << 3)]; \
      }                                                                               \
      short8 af = *(const short8*)&As[(w << 4) + l15][k0 + (g << 3)];                 \
      _Pragma("unroll")                                                               \
      for (int nt = 0; nt < 16; ++nt){                                                \
        short8 bf = *(const short8*)&Ws[cur][(nt << 4) + l15][g << 3];                \
        acc[nt] = __builtin_amdgcn_mfma_f32_16x16x32_bf16(af, bf, acc[nt], 0, 0, 0);  \
      }                                                                               \
      if (s < 7){                                                                     \
        _Pragma("unroll")                                                             \
        for (int it = 0; it < 4; ++it)                                                \
          *(short8*)&Ws[cur ^ 1][(it << 6) + (tid >> 2)][(tid & 3) << 3] = wreg[it];  \
      }                                                                               \
      __syncthreads();                                                                \
      cur ^= 1;                                                                       \
    }                                                                                 \
  }while(0)

  // ---- pass 1: K ----
  KV_LOOP(Wk);
  #pragma unroll
  for (int nt = 0; nt < 16; ++nt){
    const int col = (nt << 4) + l15;
    const float bv = b_k[col];
    #pragma unroll
    for (int r = 0; r < 4; ++r){
      const int m = m0 + row_l + r;
      float v = acc[nt][r] + bv;
      const int b_ = m >> 8, kvr = m & 255;
      const int knt = kvr >> 4, kl = kvr & 15;
      const int h = col >> 6, half = (col >> 5) & 1, kg = (col >> 3) & 3, kj = col & 7;
      kfrag[(((((size_t)(b_ * 4 + h) * 16 + knt) * 2 + half) * 4 + kg) * 16 + kl) * 8 + kj] = f2b(v);
    }
  }
  // ---- pass 2: V ----
  KV_LOOP(Wv);
  #pragma unroll
  for (int nt = 0; nt < 16; ++nt){
    const int col = (nt << 4) + l15;
    const float bv = b_v[col];
    #pragma unroll
    for (int r = 0; r < 4; ++r){
      const int m = m0 + row_l + r;
      float v = acc[nt][r] + bv;
      const int b_ = m >> 8, kvj = m & 255;
      const int jp = (kvj & ~31) | (((kvj >> 2) & 3) << 3) | (((kvj >> 4) & 1) << 2) | (kvj & 3);
      const int h = col >> 6, dp = col & 63;
      const int kk = jp >> 5, vg = (jp >> 3) & 3, vj = jp & 7;
      const int vn2 = dp >> 4, vl = dp & 15;
      vfrag[(((((size_t)(b_ * 4 + h) * 8 + kk) * 4 + vn2) * 4 + vg) * 16 + vl) * 8 + vj] = f2b(v);
    }
  }
#undef KV_LOOP
}

// -------- Q projection, 8-wave N-split (r22, verbatim) ----------------------
__global__ __launch_bounds__(512, 4) void qgemm_k(
    const float* __restrict__ node, const short* __restrict__ Wq,
    const float* __restrict__ bias,
    const float* __restrict__ lng, const float* __restrict__ lnb,
    short* __restrict__ outB)
{
  extern __shared__ __align__(16) short lds[];
  short* Ws0 = lds + 16896;
  short* Ws1 = Ws0 + 8192;
  const int tid = threadIdx.x;
  const int tile = blockIdx.x;
  const int m0 = tile << 6;
  const int w = tid >> 6, lane = tid & 63;
  const int l15 = lane & 15, g = lane >> 4;
  const int wm = w >> 1, wn = w & 1;
  const int colb = wn << 7;

#define ASW8(row_, col0_) (*(short8*)((char*)lds + (row_) * 528 + \
    (((col0_) << 1) ^ ((((row_) >> 2) & 3) << 4))))
#define ASR8(row_, boff_) (*(const short8*)((char*)lds + (row_) * 528 + \
    ((boff_) ^ ((((row_) >> 2) & 3) << 4))))
#define STGW(dst_, wmat_, s_) do{ _Pragma("unroll")                                  \
  for (int it_ = 0; it_ < 2; ++it_){ int c_ = (it_ << 9) + tid;                      \
    __builtin_amdgcn_global_load_lds(                                               \
        (const AS1 void*)((wmat_) + ((size_t)(s_) << 13) + (c_ << 3)),              \
        (AS3 void*)((dst_) + (c_ << 3)), 16, 0, 0); } }while(0)

  {
    const int row = tid >> 3, c0 = (tid & 7) << 5;
    float vv[32];
    const float* src = &node[(size_t)(m0 + row) * 256 + c0];
    #pragma unroll
    for (int i = 0; i < 8; ++i) *(f32x4*)&vv[4 * i] = *(const f32x4*)&src[4 * i];
    float s1 = 0.f, s2 = 0.f;
    #pragma unroll
    for (int i = 0; i < 32; ++i){ s1 += vv[i]; s2 += vv[i] * vv[i]; }
    s1 += __shfl_xor(s1, 1); s2 += __shfl_xor(s2, 1);
    s1 += __shfl_xor(s1, 2); s2 += __shfl_xor(s2, 2);
    s1 += __shfl_xor(s1, 4); s2 += __shfl_xor(s2, 4);
    const float mu = s1 * 0.00390625f;
    const float rs = rsqrtf(s2 * 0.00390625f - mu * mu + 1e-5f);
    #pragma unroll
    for (int i = 0; i < 4; ++i){
      const int col0 = c0 + 8 * i;
      f32x4 g0 = *(const f32x4*)&lng[col0], g1 = *(const f32x4*)&lng[col0 + 4];
      f32x4 b0 = *(const f32x4*)&lnb[col0], b1 = *(const f32x4*)&lnb[col0 + 4];
      short8 o;
      #pragma unroll
      for (int j = 0; j < 4; ++j) o[j] = f2b((vv[8 * i + j] - mu) * rs * g0[j] + b0[j]);
      #pragma unroll
      for (int j = 0; j < 4; ++j) o[4 + j] = f2b((vv[8 * i + 4 + j] - mu) * rs * g1[j] + b1[j]);
      ASW8(row, col0) = o;
    }
  }
  STGW(Ws0, Wq, 0);
  __syncthreads();

  f32x4 acc[8];
  #pragma unroll
  for (int ntl = 0; ntl < 8; ++ntl) acc[ntl] = {0.f, 0.f, 0.f, 0.f};
  {
    int cur = 0;
    #pragma unroll
    for (int s = 0; s < 8; ++s){
      short* rbuf = cur ? Ws1 : Ws0;
      short* sbuf = cur ? Ws0 : Ws1;
      if (s < 7){ STGW(sbuf, Wq, s + 1);
        asm volatile("s_waitcnt vmcnt(2)" ::: "memory");
      } else {
        asm volatile("s_waitcnt vmcnt(0)" ::: "memory");
      }
      __builtin_amdgcn_s_barrier();
      __builtin_amdgcn_sched_barrier(0);
      const short8 af = ASR8((wm << 4) + l15, (s << 6) + (g << 4));
      __builtin_amdgcn_s_setprio(1);
      #pragma unroll
      for (int ntl = 0; ntl < 8; ++ntl){
        short8 bf = *(const short8*)&rbuf[(((wn << 3) + ntl) * 16 + l15) * 32 + (g << 3)];
        acc[ntl] = __builtin_amdgcn_mfma_f32_16x16x32_bf16(af, bf, acc[ntl], 0, 0, 0);
      }
      __builtin_amdgcn_s_setprio(0);
      __builtin_amdgcn_s_barrier();
      __builtin_amdgcn_sched_barrier(0);
      cur ^= 1;
    }
  }
  #pragma unroll
  for (int ntl = 0; ntl < 8; ++ntl){
    const int col = colb + (ntl << 4) + l15;
    const float bv = bias[col];
    #pragma unroll
    for (int r = 0; r < 4; ++r){
      float v = acc[ntl][r] + bv;
      outB[((((size_t)tile * 8 + (col >> 5)) * 4 + wm) * 64
            + (((col >> 3) & 3) << 4) + (g << 2) + r) * 8 + (col & 7)] = f2b(v);
    }
  }
#undef ASW8
#undef ASR8
#undef STGW
}

// ---------------- split-KV fused MFMA attention -----------------------------
// Block: 512 thr = 8 waves = 4 q-groups (wq) x 2 kv-halves (wk); 64 q-rows.
// Grid 64x8 = 512 blocks -> 4096 waves = 16 waves/CU (2 blocks/CU).
// Wave (wq,wk): 16 q-rows, kv in [128wk, 128wk+128). Softmax max/sum combined
// across halves via 1KB LDS exchange (LDS-only raw barriers so the K(h+1)
// global_load_lds stays in flight). PV partial over kk in [4wk,4wk+4);
// partial-ctx exchanged through the Vl region after PV reads complete.
__global__ __launch_bounds__(512, 4) void attn_k(
    const short* __restrict__ Qf, const short* __restrict__ Kf,
    const short* __restrict__ Vf, const float* __restrict__ cw,
    short* __restrict__ ctx, float* __restrict__ am_out)
{
  extern __shared__ __align__(16) short smem[];   // 66560 B
  short* Kl = smem;                               // 32KB
  short* Vl = smem + 16384;                       // 32KB (also cw bounce / obuf)
  float* mb = (float*)((char*)smem + 65536);      // mbuf[64][2]
  float* sb = mb + 128;                           // sbuf[64][2]
  const int b = blockIdx.y;
  const int q0 = blockIdx.x << 6;
  const int tid = threadIdx.x;
  const int w = tid >> 6, lane = tid & 63;
  const int l15 = lane & 15, g = lane >> 4;
  const int wq = w >> 1, wk = w & 1;
  const int arow = (wq << 4) + l15;               // wave's q-row within block
  const size_t qw = (size_t)b * 4096 + q0 + (wq << 4);
  const size_t qblk = qw >> 4;
  const size_t tileQ = qblk >> 2;
  const int wQ = (int)(qblk & 3);
  const size_t tileC = (size_t)b * 64 + blockIdx.x;

#define STG(dst_, src_) do{ _Pragma("unroll")                                        \
  for (int it_ = 0; it_ < 4; ++it_){ int c_ = (it_ << 9) + tid;                      \
    __builtin_amdgcn_global_load_lds((const AS1 void*)((src_) + (c_ << 3)),          \
                                     (AS3 void*)((dst_) + (c_ << 3)), 16, 0, 0); } }while(0)
#define LBAR() do{ asm volatile("s_waitcnt lgkmcnt(0)" ::: "memory");                \
  __builtin_amdgcn_s_barrier(); __builtin_amdgcn_sched_barrier(0); }while(0)

  STG(Kl, Kf + ((size_t)(b * 4) << 14));          // K(0) overlaps the cw phase

  // ---- cw: rows w*8..w*8+7 coalesced -> swizzled bounce in Vl -> packed regs
  unsigned cwp[8][2];
  f32x4 am[8];
  {
    char* reg = (char*)Vl;
    #pragma unroll
    for (int jj = 0; jj < 8; ++jj){
      const int row = (w << 3) + jj;
      f32x4 v = *(const f32x4*)&cw[((size_t)b * 4096 + q0 + row) * 256 + (lane << 2)];
      u32x2 d = { pk2(v[0], v[1]), pk2(v[2], v[3]) };
      unsigned off = ((unsigned)(row << 9) + (lane << 3)) ^ ((row & 7) << 4);
      *(u32x2*)(reg + off) = d;
    }
    __syncthreads();
    #pragma unroll
    for (int nt = 0; nt < 8; ++nt){
      const int ntp = (wk << 3) + nt;
      unsigned base = ((unsigned)(arow << 9) + (ntp << 5) + (g << 3)) ^ ((arow & 7) << 4);
      cwp[nt][0] = *(const unsigned*)(reg + base);
      cwp[nt][1] = *(const unsigned*)(reg + base + 4);
      am[nt] = {0.f, 0.f, 0.f, 0.f};
    }
    __syncthreads();                              // K(0) certified; Vl free
  }

  for (int h = 0; h < 4; ++h){
    STG(Vl, Vf + ((size_t)(b * 4 + h) << 14));
    short8 qf0 = *(const short8*)&Qf[(((tileQ * 8 + (h << 1)) * 4 + wQ) * 64 + lane) * 8];
    short8 qf1 = *(const short8*)&Qf[(((tileQ * 8 + (h << 1) + 1) * 4 + wQ) * 64 + lane) * 8];

    // ---- QK^T over this wave's kv half ----
    f32x4 acc[8];
    #pragma unroll
    for (int nt = 0; nt < 8; ++nt) acc[nt] = {0.f, 0.f, 0.f, 0.f};
    __builtin_amdgcn_s_setprio(1);
    #pragma unroll
    for (int nt = 0; nt < 8; ++nt){
      const int ntp = (wk << 3) + nt;
      short8 kf0 = *(const short8*)&Kl[(ntp << 10) + (lane << 3)];
      acc[nt] = __builtin_amdgcn_mfma_f32_16x16x32_bf16(kf0, qf0, acc[nt], 0, 0, 0);
      short8 kf1 = *(const short8*)&Kl[(ntp << 10) + 512 + (lane << 3)];
      acc[nt] = __builtin_amdgcn_mfma_f32_16x16x32_bf16(kf1, qf1, acc[nt], 0, 0, 0);
    }
    __builtin_amdgcn_s_setprio(0);
    __syncthreads();                   // V staged; all waves done reading Kl
    if (h < 3) STG(Kl, Kf + ((size_t)(b * 4 + h + 1) << 14));

    // ---- softmax with cross-half exchange ----
    float mx = -3.4e38f;
    #pragma unroll
    for (int nt = 0; nt < 8; ++nt){
      float c0 = ulo(cwp[nt][0]), c1 = uhi(cwp[nt][0]);
      float c2 = ulo(cwp[nt][1]), c3 = uhi(cwp[nt][1]);
      acc[nt][0] = acc[nt][0] * 0.125f + c0;
      acc[nt][1] = acc[nt][1] * 0.125f + c1;
      acc[nt][2] = acc[nt][2] * 0.125f + c2;
      acc[nt][3] = acc[nt][3] * 0.125f + c3;
      mx = fmaxf(mx, fmaxf(fmaxf(acc[nt][0], acc[nt][1]), fmaxf(acc[nt][2], acc[nt][3])));
    }
    mx = fmaxf(mx, __shfl_xor(mx, 16));
    mx = fmaxf(mx, __shfl_xor(mx, 32));
    if (g == 0) mb[arow * 2 + wk] = mx;
    LBAR();
    const float m = fmaxf(mb[arow * 2], mb[arow * 2 + 1]);
    float sm = 0.f;
    #pragma unroll
    for (int nt = 0; nt < 8; ++nt){
      #pragma unroll
      for (int r = 0; r < 4; ++r){
        float e = __expf(acc[nt][r] - m);
        acc[nt][r] = e; sm += e;
      }
    }
    sm += __shfl_xor(sm, 16);
    sm += __shfl_xor(sm, 32);
    if (g == 0) sb[arow * 2 + wk] = sm;
    LBAR();
    const float inv = 1.f / (sb[arow * 2] + sb[arow * 2 + 1]);
    #pragma unroll
    for (int nt = 0; nt < 8; ++nt){
      #pragma unroll
      for (int r = 0; r < 4; ++r){
        float p = acc[nt][r] * inv;
        acc[nt][r] = p;
        am[nt][r] += 0.25f * p;
      }
    }
    // ---- PV partial over kk in [4wk, 4wk+4) ----
    f32x4 oc[4] = {{0,0,0,0},{0,0,0,0},{0,0,0,0},{0,0,0,0}};
    __builtin_amdgcn_s_setprio(1);
    #pragma unroll
    for (int kkl = 0; kkl < 4; ++kkl){
      const int kkg = (wk << 2) + kkl;
      union { short8 s; unsigned u[4]; } pa;
      pa.u[0] = pk2(acc[2 * kkl][0],     acc[2 * kkl][1]);
      pa.u[1] = pk2(acc[2 * kkl][2],     acc[2 * kkl][3]);
      pa.u[2] = pk2(acc[2 * kkl + 1][0], acc[2 * kkl + 1][1]);
      pa.u[3] = pk2(acc[2 * kkl + 1][2], acc[2 * kkl + 1][3]);
      #pragma unroll
      for (int n2 = 0; n2 < 4; ++n2){
        short8 vb = *(const short8*)&Vl[(((kkg << 2) + n2) << 9) + (lane << 3)];
        oc[n2] = __builtin_amdgcn_mfma_f32_16x16x32_bf16(pa.s, vb, oc[n2], 0, 0, 0);
      }
    }
    __builtin_amdgcn_s_setprio(0);
    LBAR();                            // all waves done reading Vl
    // ---- partial-ctx exchange through Vl ----
    float* obuf = (float*)Vl;
    if (wk == 0){
      #pragma unroll
      for (int n2 = 0; n2 < 4; ++n2)
        *(f32x4*)&obuf[wq * 1024 + n2 * 256 + lane * 4] = oc[n2];
    }
    LBAR();
    if (wk == 1){
      #pragma unroll
      for (int n2 = 0; n2 < 4; ++n2){
        f32x4 t = *(const f32x4*)&obuf[wq * 1024 + n2 * 256 + lane * 4];
        const int sctx = (h << 1) + (n2 >> 1);
        const int gctx = ((n2 & 1) << 1) + (l15 >> 3);
        const int j = l15 & 7;
        #pragma unroll
        for (int r = 0; r < 4; ++r)
          ctx[(((tileC * 8 + sctx) * 4 + wq) * 64 + (gctx << 4) + (g << 2) + r) * 8 + j]
              = f2b(oc[n2][r] + t[r]);
      }
    }
    __syncthreads();                   // K(h+1) certified; obuf reads done
  }

  // ---- am: scatter into swizzled 64KB smem, then coalesced stores ----
  {
    #pragma unroll
    for (int nt = 0; nt < 8; ++nt){
      unsigned off = ((unsigned)(wq << 14) + (l15 << 10) + (wk << 9) + (nt << 6) + (g << 4))
                   ^ ((l15 & 7) << 4);
      *(f32x4*)((char*)smem + off) = am[nt];
    }
    LBAR();
    #pragma unroll
    for (int i2 = 0; i2 < 8; ++i2){
      unsigned fb = (tid << 4) + (i2 << 13);
      unsigned row = fb >> 10;
      f32x4 v = *(const f32x4*)((char*)smem + (fb ^ ((row & 7) << 4)));
      *(f32x4*)&am_out[((size_t)b * 4096 + q0 + row) * 256 + ((fb & 1023) >> 2)] = v;
    }
  }
#undef STG
#undef LBAR
}

// ---------------- fused tail, 8-wave N-split (r22, verbatim) ----------------
__global__ __launch_bounds__(512, 4) void tail_k(
    const short* __restrict__ ctxaf, const short* __restrict__ Wst,
    const float* __restrict__ b_o, const float* __restrict__ b_m1,
    const float* __restrict__ b_m2, const float* __restrict__ node,
    const float* __restrict__ lng, const float* __restrict__ lnb,
    float* __restrict__ outF)
{
  extern __shared__ __align__(16) short lds[];
  short* Ws0 = lds + 16896;
  short* Ws1 = Ws0 + 8192;
  float* part = (float*)(lds + 33280);
  const int tid = threadIdx.x;
  const int tile = blockIdx.x;
  const int m0 = tile << 6;
  const int w = tid >> 6, lane = tid & 63;
  const int l15 = lane & 15, g = lane >> 4;
  const int wm = w >> 1, wn = w & 1;
  const int row_l = (wm << 4) + (g << 2);
  const int colb = wn << 7;

#define ASW(row_, col_) (*(short*)((char*)lds + (row_) * 528 + \
    (((col_) ^ ((((row_) >> 2) & 3) << 3)) << 1)))
#define ASR8(row_, boff_) (*(const short8*)((char*)lds + (row_) * 528 + \
    ((boff_) ^ ((((row_) >> 2) & 3) << 4))))
#define STGW(dst_, wmat_, s_) do{ _Pragma("unroll")                                  \
  for (int it_ = 0; it_ < 2; ++it_){ int c_ = (it_ << 9) + tid;                      \
    __builtin_amdgcn_global_load_lds(                                               \
        (const AS1 void*)((wmat_) + ((size_t)(s_) << 13) + (c_ << 3)),              \
        (AS3 void*)((dst_) + (c_ << 3)), 16, 0, 0); } }while(0)
#define KLOOP(WMAT, AF_EXPR)                                                         \
  do{ int cur = 0;                                                                   \
    _Pragma("unroll")                                                                \
    for (int s = 0; s < 8; ++s){                                                     \
      short* rbuf = cur ? Ws1 : Ws0;                                                 \
      short* sbuf = cur ? Ws0 : Ws1;                                                 \
      if (s < 7){ STGW(sbuf, WMAT, s + 1);                                           \
        asm volatile("s_waitcnt vmcnt(2)" ::: "memory");                             \
      } else {                                                                       \
        asm volatile("s_waitcnt vmcnt(0)" ::: "memory");                             \
      }                                                                              \
      __builtin_amdgcn_s_barrier();                                                  \
      __builtin_amdgcn_sched_barrier(0);                                             \
      const short8 af = (AF_EXPR);                                                   \
      __builtin_amdgcn_s_setprio(1);                                                 \
      _Pragma("unroll")                                                              \
      for (int ntl = 0; ntl < 8; ++ntl){                                             \
        short8 bf = *(const short8*)&rbuf[(((wn << 3) + ntl) * 16 + l15) * 32 + (g << 3)]; \
        acc[ntl] = __builtin_amdgcn_mfma_f32_16x16x32_bf16(af, bf, acc[ntl], 0, 0, 0); \
      }                                                                              \
      __builtin_amdgcn_s_setprio(0);                                                 \
      __builtin_amdgcn_s_barrier();                                                  \
      __builtin_amdgcn_sched_barrier(0);                                             \
      cur ^= 1;                                                                      \
    } }while(0)

  f32x4 acc[8];

  STGW(Ws0, Wst, 0);
  short8 afr[8];
  #pragma unroll
  for (int s = 0; s < 8; ++s)
    afr[s] = *(const short8*)&ctxaf[((((size_t)tile << 3) + s) * 4 + wm) * 512 + (lane << 3)];
  #pragma unroll
  for (int ntl = 0; ntl < 8; ++ntl) acc[ntl] = {0.f, 0.f, 0.f, 0.f};
  KLOOP(Wst, afr[s]);

  unsigned xvp[8][2];
  #pragma unroll
  for (int ntl = 0; ntl < 8; ++ntl){
    const int col = colb + (ntl << 4) + l15;
    const float bv = b_o[col];
    float x0 = acc[ntl][0] + bv + node[(size_t)(m0 + row_l + 0) * 256 + col];
    float x1 = acc[ntl][1] + bv + node[(size_t)(m0 + row_l + 1) * 256 + col];
    float x2 = acc[ntl][2] + bv + node[(size_t)(m0 + row_l + 2) * 256 + col];
    float x3 = acc[ntl][3] + bv + node[(size_t)(m0 + row_l + 3) * 256 + col];
    xvp[ntl][0] = pk2(x0, x1);
    xvp[ntl][1] = pk2(x2, x3);
  }
  #pragma unroll
  for (int r = 0; r < 4; ++r){
    float s1 = 0.f, s2 = 0.f;
    #pragma unroll
    for (int ntl = 0; ntl < 8; ++ntl){
      float v = (r == 0) ? ulo(xvp[ntl][0]) : (r == 1) ? uhi(xvp[ntl][0])
              : (r == 2) ? ulo(xvp[ntl][1]) : uhi(xvp[ntl][1]);
      s1 += v; s2 += v * v;
    }
    #pragma unroll
    for (int off = 1; off < 16; off <<= 1){ s1 += __shfl_xor(s1, off); s2 += __shfl_xor(s2, off); }
    if (l15 == 0){
      part[((row_l + r) * 2 + wn) * 2]     = s1;
      part[((row_l + r) * 2 + wn) * 2 + 1] = s2;
    }
  }
  __syncthreads();
  #pragma unroll
  for (int r = 0; r < 4; ++r){
    const int row = row_l + r;
    const float S1 = part[(row * 2) * 2]     + part[(row * 2 + 1) * 2];
    const float S2 = part[(row * 2) * 2 + 1] + part[(row * 2 + 1) * 2 + 1];
    const float mu = S1 * 0.00390625f;
    const float rs = rsqrtf(S2 * 0.00390625f - mu * mu + 1e-5f);
    #pragma unroll
    for (int ntl = 0; ntl < 8; ++ntl){
      const int col = colb + (ntl << 4) + l15;
      float v = (r == 0) ? ulo(xvp[ntl][0]) : (r == 1) ? uhi(xvp[ntl][0])
              : (r == 2) ? ulo(xvp[ntl][1]) : uhi(xvp[ntl][1]);
      ASW(row, col) = f2b((v - mu) * rs * lng[col] + lnb[col]);
    }
  }

  {
    const short* Wm1 = Wst + 65536;
    STGW(Ws0, Wm1, 0);
    __syncthreads();
    #pragma unroll
    for (int ntl = 0; ntl < 8; ++ntl) acc[ntl] = {0.f, 0.f, 0.f, 0.f};
    KLOOP(Wm1, ASR8((wm << 4) + l15, (s << 6) + (g << 4)));
  }
  #pragma unroll
  for (int ntl = 0; ntl < 8; ++ntl){
    const int col = colb + (ntl << 4) + l15;
    const float bv = b_m1[col];
    #pragma unroll
    for (int r = 0; r < 4; ++r){
      float v = acc[ntl][r] + bv;
      v = 0.5f * v * (1.0f + erff(v * 0.70710678118f));
      ASW(row_l + r, col) = f2b(v);
    }
  }

  {
    const short* Wm2 = Wst + 131072;
    STGW(Ws0, Wm2, 0);
    __syncthreads();
    #pragma unroll
    for (int ntl = 0; ntl < 8; ++ntl) acc[ntl] = {0.f, 0.f, 0.f, 0.f};
    KLOOP(Wm2, ASR8((wm << 4) + l15, (s << 6) + (g << 4)));
  }
  #pragma unroll
  for (int ntl = 0; ntl < 8; ++ntl){
    const int col = colb + (ntl << 4) + l15;
    const float bv = b_m2[col];
    #pragma unroll
    for (int r = 0; r < 4; ++r){
      float xr = (r == 0) ? ulo(xvp[ntl][0]) : (r == 1) ? uhi(xvp[ntl][0])
               : (r == 2) ? ulo(xvp[ntl][1]) : uhi(xvp[ntl][1]);
      outF[(size_t)(m0 + row_l + r) * 256 + col] = acc[ntl][r] + bv + xr;
    }
  }
#undef ASW
#undef ASR8
#undef STGW
#undef KLOOP
}

extern "C" void kernel_launch(void* const* d_in, const int* in_sizes, int n_in,
                              void* d_out, int out_size, void* d_ws, size_t ws_size,
                              hipStream_t stream)
{
  const float* node_emb = (const float*)d_in[0];
  const float* cluster  = (const float*)d_in[1];
  const float* cw       = (const float*)d_in[2];
  const float* ln_q_g   = (const float*)d_in[3];
  const float* ln_q_b   = (const float*)d_in[4];
  const float* ln_kv_g  = (const float*)d_in[5];
  const float* ln_kv_b  = (const float*)d_in[6];
  const float* ln_o_g   = (const float*)d_in[7];
  const float* ln_o_b   = (const float*)d_in[8];
  const float* W_q  = (const float*)d_in[9];  const float* b_q  = (const float*)d_in[10];
  const float* W_k  = (const float*)d_in[11]; const float* b_k  = (const float*)d_in[12];
  const float* W_v  = (const float*)d_in[13]; const float* b_v  = (const float*)d_in[14];
  const float* W_o  = (const float*)d_in[15]; const float* b_o  = (const float*)d_in[16];
  const float* W_m1 = (const float*)d_in[17]; const float* b_m1 = (const float*)d_in[18];
  const float* W_m2 = (const float*)d_in[19]; const float* b_m2 = (const float*)d_in[20];

  char* ws = (char*)d_ws;
  short* Wbf   = (short*)ws;                                   // 786,432 B row-major (6 mats)
  short* Wst   = (short*)(ws + 786432);                        // 524,288 B stage-order (O,M1,M2,Q)
  short* bufA  = (short*)(ws + 1310720);                       // 16.78 MB: ctx afrag
  short* bufB  = (short*)(ws + 1310720 + 16777216);            // 16.78 MB: Q afrag
  short* kfrag = (short*)(ws + 1310720 + 2 * 16777216);
  short* vfrag = (short*)(ws + 1310720 + 2 * 16777216 + 1048576);

  float* outF = (float*)d_out;            // final out (written only by tail_k)
  float* amof = (float*)d_out + 8388608;  // attn_matrix

  hipFuncSetAttribute((const void*)attn_k,  hipFuncAttributeMaxDynamicSharedMemorySize, 66560);
  hipFuncSetAttribute((const void*)tail_k,  hipFuncAttributeMaxDynamicSharedMemorySize, 67584);
  hipFuncSetAttribute((const void*)qgemm_k, hipFuncAttributeMaxDynamicSharedMemorySize, 66560);

  cvt_w<<<1536, 256, 0, stream>>>(W_q, W_k, W_v, W_o, W_m1, W_m2, Wbf, Wst);
  // fused K+V projection (LN(cluster) once) -> kfrag / vfrag
  kv_k<<<32, 256, 0, stream>>>(cluster, Wbf + 65536, Wbf + 131072,
      b_k, b_v, ln_kv_g, ln_kv_b, kfrag, vfrag);
  // Q projection: 8-wave, fused input-LN, afrag output -> bufB
  qgemm_k<<<512, 512, 66560, stream>>>(node_emb, Wst + 196608, b_q,
      ln_q_g, ln_q_b, bufB);
  // split-KV attention (ctx afrag -> bufA, attn_matrix -> d_out 2nd half)
  attn_k<<<dim3(64, 8), 512, 66560, stream>>>(bufB, kfrag, vfrag, cw, bufA, amof);
  // fused tail: O(+res)+LN -> M1(+GELU) -> M2(+res) -> out (8-wave blocks)
  tail_k<<<512, 512, 67584, stream>>>(bufA, Wst, b_o, b_m1, b_m2,
      node_emb, ln_o_g, ln_o_b, outF);
}

// Round 24
// 115.479 us; speedup vs baseline: 1.1551x; 1.1551x over previous
//
#include <hip/hip_runtime.h>
#include <math.h>

typedef __attribute__((ext_vector_type(8))) short short8;
typedef __attribute__((ext_vector_type(4))) float f32x4;
typedef __attribute__((ext_vector_type(2))) unsigned int u32x2;

#define AS1 __attribute__((address_space(1)))
#define AS3 __attribute__((address_space(3)))

__device__ __forceinline__ float b2f(short s){
  return __uint_as_float(((unsigned int)(unsigned short)s) << 16);
}
__device__ __forceinline__ short f2b(float f){
  unsigned int u = __float_as_uint(f);
  u = (u + 0x7fffu + ((u >> 16) & 1u)) >> 16;
  return (short)u;
}
__device__ __forceinline__ unsigned pk2(float lo, float hi){
  return ((unsigned)(unsigned short)f2b(hi) << 16) | (unsigned)(unsigned short)f2b(lo);
}
__device__ __forceinline__ float ulo(unsigned u){ return __uint_as_float(u << 16); }
__device__ __forceinline__ float uhi(unsigned u){ return __uint_as_float(u & 0xffff0000u); }

// ---------------- weight f32 -> bf16 ----------------
// dst: row-major (6 mats). dstS: stage-order [s][row][g][8], slots
// {0:W_o, 1:W_m1, 2:W_m2, 3:W_q}.
__global__ __launch_bounds__(256) void cvt_w(
    const float* __restrict__ s0, const float* __restrict__ s1,
    const float* __restrict__ s2, const float* __restrict__ s3,
    const float* __restrict__ s4, const float* __restrict__ s5,
    short* __restrict__ dst, short* __restrict__ dstS)
{
  const float* srcs[6] = {s0, s1, s2, s3, s4, s5};
  int i = blockIdx.x * 256 + threadIdx.x;       // 6*65536 total
  int mat = i >> 16, rc = i & 65535;
  short v = f2b(srcs[mat][rc]);
  dst[i] = v;
  int slot = (mat >= 3) ? (mat - 3) : (mat == 0 ? 3 : -1);
  if (slot >= 0){
    int row = rc >> 8, col = rc & 255;
    int d2 = slot * 65536 + ((col >> 5) << 13) + (row << 5)
           + (((col >> 3) & 3) << 3) + (col & 7);
    dstS[d2] = v;
  }
}

// -------- fused K+V projection: LN(cluster) once, two k-loops, frag outs ----
__global__ __launch_bounds__(256, 2) void kv_k(
    const float* __restrict__ cluster,
    const short* __restrict__ Wk, const short* __restrict__ Wv,
    const float* __restrict__ b_k, const float* __restrict__ b_v,
    const float* __restrict__ lng, const float* __restrict__ lnb,
    short* __restrict__ kfrag, short* __restrict__ vfrag)
{
  __shared__ short As[64][264];
  __shared__ short Ws[2][256][40];
  const int tid = threadIdx.x;
  const int m0 = blockIdx.x << 6;
  const int w = tid >> 6, lane = tid & 63;
  const int l15 = lane & 15, g = lane >> 4;

  // ---- LN prologue (reads cluster once) ----
  {
    const int row = tid >> 2, c0 = (tid & 3) << 6;
    float vv[64];
    const float* src = &cluster[(size_t)(m0 + row) * 256 + c0];
    #pragma unroll
    for (int i = 0; i < 16; ++i) *(f32x4*)&vv[4 * i] = *(const f32x4*)&src[4 * i];
    float s1 = 0.f, s2 = 0.f;
    #pragma unroll
    for (int i = 0; i < 64; ++i){ s1 += vv[i]; s2 += vv[i] * vv[i]; }
    s1 += __shfl_xor(s1, 1); s2 += __shfl_xor(s2, 1);
    s1 += __shfl_xor(s1, 2); s2 += __shfl_xor(s2, 2);
    const float mu = s1 * 0.00390625f;
    const float rs = rsqrtf(s2 * 0.00390625f - mu * mu + 1e-5f);
    #pragma unroll
    for (int i = 0; i < 8; ++i){
      f32x4 gv0 = *(const f32x4*)&lng[c0 + 8 * i];
      f32x4 gv1 = *(const f32x4*)&lng[c0 + 8 * i + 4];
      f32x4 bv0 = *(const f32x4*)&lnb[c0 + 8 * i];
      f32x4 bv1 = *(const f32x4*)&lnb[c0 + 8 * i + 4];
      short8 o;
      #pragma unroll
      for (int j = 0; j < 4; ++j) o[j] = f2b((vv[8 * i + j] - mu) * rs * gv0[j] + bv0[j]);
      #pragma unroll
      for (int j = 0; j < 4; ++j) o[4 + j] = f2b((vv[8 * i + 4 + j] - mu) * rs * gv1[j] + bv1[j]);
      *(short8*)&As[row][c0 + 8 * i] = o;
    }
  }

  f32x4 acc[16];
  const int row_l = (w << 4) + (g << 2);

#define KV_LOOP(WMAT)                                                                 \
  do{                                                                                 \
    _Pragma("unroll")                                                                 \
    for (int it = 0; it < 4; ++it){                                                   \
      int row = (it << 6) + (tid >> 2), c = (tid & 3) << 3;                           \
      *(short8*)&Ws[0][row][c] = *(const short8*)&(WMAT)[(size_t)row * 256 + c];      \
    }                                                                                 \
    __syncthreads();                                                                  \
    _Pragma("unroll")                                                                 \
    for (int nt = 0; nt < 16; ++nt) acc[nt] = (f32x4){0.f, 0.f, 0.f, 0.f};            \
    int cur = 0;                                                                      \
    for (int s = 0; s < 8; ++s){                                                      \
      const int k0 = s << 5;                                                          \
      short8 wreg[4];                                                                 \
      if (s < 7){                                                                     \
        _Pragma("unroll")                                                             \
        for (int it = 0; it < 4; ++it)                                                \
          wreg[it] = *(const short8*)&(WMAT)[(size_t)((it << 6) + (tid >> 2)) * 256 + k0 + 32 + ((tid & 3) << 3)]; \
      }                                                                               \
      short8 af = *(const short8*)&As[(w << 4) + l15][k0 + (g << 3)];                 \
      _Pragma("unroll")                                                               \
      for (int nt = 0; nt < 16; ++nt){                                                \
        short8 bf = *(const short8*)&Ws[cur][(nt << 4) + l15][g << 3];                \
        acc[nt] = __builtin_amdgcn_mfma_f32_16x16x32_bf16(af, bf, acc[nt], 0, 0, 0);  \
      }                                                                               \
      if (s < 7){                                                                     \
        _Pragma("unroll")                                                             \
        for (int it = 0; it < 4; ++it)                                                \
          *(short8*)&Ws[cur ^ 1][(it << 6) + (tid >> 2)][(tid & 3) << 3] = wreg[it];  \
      }                                                                               \
      __syncthreads();                                                                \
      cur ^= 1;                                                                       \
    }                                                                                 \
  }while(0)

  // ---- pass 1: K ----
  KV_LOOP(Wk);
  #pragma unroll
  for (int nt = 0; nt < 16; ++nt){
    const int col = (nt << 4) + l15;
    const float bv = b_k[col];
    #pragma unroll
    for (int r = 0; r < 4; ++r){
      const int m = m0 + row_l + r;
      float v = acc[nt][r] + bv;
      const int b_ = m >> 8, kvr = m & 255;
      const int knt = kvr >> 4, kl = kvr & 15;
      const int h = col >> 6, half = (col >> 5) & 1, kg = (col >> 3) & 3, kj = col & 7;
      kfrag[(((((size_t)(b_ * 4 + h) * 16 + knt) * 2 + half) * 4 + kg) * 16 + kl) * 8 + kj] = f2b(v);
    }
  }
  // ---- pass 2: V ----
  KV_LOOP(Wv);
  #pragma unroll
  for (int nt = 0; nt < 16; ++nt){
    const int col = (nt << 4) + l15;
    const float bv = b_v[col];
    #pragma unroll
    for (int r = 0; r < 4; ++r){
      const int m = m0 + row_l + r;
      float v = acc[nt][r] + bv;
      const int b_ = m >> 8, kvj = m & 255;
      const int jp = (kvj & ~31) | (((kvj >> 2) & 3) << 3) | (((kvj >> 4) & 1) << 2) | (kvj & 3);
      const int h = col >> 6, dp = col & 63;
      const int kk = jp >> 5, vg = (jp >> 3) & 3, vj = jp & 7;
      const int vn2 = dp >> 4, vl = dp & 15;
      vfrag[(((((size_t)(b_ * 4 + h) * 8 + kk) * 4 + vn2) * 4 + vg) * 16 + vl) * 8 + vj] = f2b(v);
    }
  }
#undef KV_LOOP
}

// -------- Q projection, 8-wave N-split (r22, verbatim) ----------------------
__global__ __launch_bounds__(512, 4) void qgemm_k(
    const float* __restrict__ node, const short* __restrict__ Wq,
    const float* __restrict__ bias,
    const float* __restrict__ lng, const float* __restrict__ lnb,
    short* __restrict__ outB)
{
  extern __shared__ __align__(16) short lds[];
  short* Ws0 = lds + 16896;
  short* Ws1 = Ws0 + 8192;
  const int tid = threadIdx.x;
  const int tile = blockIdx.x;
  const int m0 = tile << 6;
  const int w = tid >> 6, lane = tid & 63;
  const int l15 = lane & 15, g = lane >> 4;
  const int wm = w >> 1, wn = w & 1;
  const int colb = wn << 7;

#define ASW8(row_, col0_) (*(short8*)((char*)lds + (row_) * 528 + \
    (((col0_) << 1) ^ ((((row_) >> 2) & 3) << 4))))
#define ASR8(row_, boff_) (*(const short8*)((char*)lds + (row_) * 528 + \
    ((boff_) ^ ((((row_) >> 2) & 3) << 4))))
#define STGW(dst_, wmat_, s_) do{ _Pragma("unroll")                                  \
  for (int it_ = 0; it_ < 2; ++it_){ int c_ = (it_ << 9) + tid;                      \
    __builtin_amdgcn_global_load_lds(                                               \
        (const AS1 void*)((wmat_) + ((size_t)(s_) << 13) + (c_ << 3)),              \
        (AS3 void*)((dst_) + (c_ << 3)), 16, 0, 0); } }while(0)

  {
    const int row = tid >> 3, c0 = (tid & 7) << 5;
    float vv[32];
    const float* src = &node[(size_t)(m0 + row) * 256 + c0];
    #pragma unroll
    for (int i = 0; i < 8; ++i) *(f32x4*)&vv[4 * i] = *(const f32x4*)&src[4 * i];
    float s1 = 0.f, s2 = 0.f;
    #pragma unroll
    for (int i = 0; i < 32; ++i){ s1 += vv[i]; s2 += vv[i] * vv[i]; }
    s1 += __shfl_xor(s1, 1); s2 += __shfl_xor(s2, 1);
    s1 += __shfl_xor(s1, 2); s2 += __shfl_xor(s2, 2);
    s1 += __shfl_xor(s1, 4); s2 += __shfl_xor(s2, 4);
    const float mu = s1 * 0.00390625f;
    const float rs = rsqrtf(s2 * 0.00390625f - mu * mu + 1e-5f);
    #pragma unroll
    for (int i = 0; i < 4; ++i){
      const int col0 = c0 + 8 * i;
      f32x4 g0 = *(const f32x4*)&lng[col0], g1 = *(const f32x4*)&lng[col0 + 4];
      f32x4 b0 = *(const f32x4*)&lnb[col0], b1 = *(const f32x4*)&lnb[col0 + 4];
      short8 o;
      #pragma unroll
      for (int j = 0; j < 4; ++j) o[j] = f2b((vv[8 * i + j] - mu) * rs * g0[j] + b0[j]);
      #pragma unroll
      for (int j = 0; j < 4; ++j) o[4 + j] = f2b((vv[8 * i + 4 + j] - mu) * rs * g1[j] + b1[j]);
      ASW8(row, col0) = o;
    }
  }
  STGW(Ws0, Wq, 0);
  __syncthreads();

  f32x4 acc[8];
  #pragma unroll
  for (int ntl = 0; ntl < 8; ++ntl) acc[ntl] = {0.f, 0.f, 0.f, 0.f};
  {
    int cur = 0;
    #pragma unroll
    for (int s = 0; s < 8; ++s){
      short* rbuf = cur ? Ws1 : Ws0;
      short* sbuf = cur ? Ws0 : Ws1;
      if (s < 7){ STGW(sbuf, Wq, s + 1);
        asm volatile("s_waitcnt vmcnt(2)" ::: "memory");
      } else {
        asm volatile("s_waitcnt vmcnt(0)" ::: "memory");
      }
      __builtin_amdgcn_s_barrier();
      __builtin_amdgcn_sched_barrier(0);
      const short8 af = ASR8((wm << 4) + l15, (s << 6) + (g << 4));
      __builtin_amdgcn_s_setprio(1);
      #pragma unroll
      for (int ntl = 0; ntl < 8; ++ntl){
        short8 bf = *(const short8*)&rbuf[(((wn << 3) + ntl) * 16 + l15) * 32 + (g << 3)];
        acc[ntl] = __builtin_amdgcn_mfma_f32_16x16x32_bf16(af, bf, acc[ntl], 0, 0, 0);
      }
      __builtin_amdgcn_s_setprio(0);
      __builtin_amdgcn_s_barrier();
      __builtin_amdgcn_sched_barrier(0);
      cur ^= 1;
    }
  }
  #pragma unroll
  for (int ntl = 0; ntl < 8; ++ntl){
    const int col = colb + (ntl << 4) + l15;
    const float bv = bias[col];
    #pragma unroll
    for (int r = 0; r < 4; ++r){
      float v = acc[ntl][r] + bv;
      outB[((((size_t)tile * 8 + (col >> 5)) * 4 + wm) * 64
            + (((col >> 3) & 3) << 4) + (g << 2) + r) * 8 + (col & 7)] = f2b(v);
    }
  }
#undef ASW8
#undef ASR8
#undef STGW
}

// ---------------- fused MFMA attention (r21/r22 proven, verbatim) -----------
__global__ __launch_bounds__(256, 2) void attn_k(
    const short* __restrict__ Qf, const short* __restrict__ Kf,
    const short* __restrict__ Vf, const float* __restrict__ cw,
    short* __restrict__ ctx, float* __restrict__ am_out)
{
  extern __shared__ __align__(16) short smem[];   // 32768 shorts = 64KB
  short* Kl = smem;
  short* Vl = smem + 16384;
  const int b = blockIdx.y;
  const int q0 = blockIdx.x << 6;
  const int tid = threadIdx.x;
  const int w = tid >> 6, lane = tid & 63;
  const int l15 = lane & 15, g = lane >> 4;
  const size_t qw = (size_t)b * 4096 + q0 + (w << 4);
  const size_t qblk = qw >> 4;
  const size_t tileQ = qblk >> 2;
  const int wQ = (int)(qblk & 3);
  const size_t tileC = (size_t)b * 64 + blockIdx.x;

#define STG(dst_, src_) do{ _Pragma("unroll")                                        \
  for (int it_ = 0; it_ < 8; ++it_){ int c_ = (it_ << 8) + tid;                      \
    __builtin_amdgcn_global_load_lds((const AS1 void*)((src_) + (c_ << 3)),          \
                                     (AS3 void*)((dst_) + (c_ << 3)), 16, 0, 0); } }while(0)

  STG(Kl, Kf + ((size_t)(b * 4) << 14));          // K(0) overlaps the cw phase

  unsigned cwp[16][2];
  f32x4 am[16];
  {
    char* reg = (char*)smem + 32768 + (w << 13);  // bounce scratch in Vl region
    #pragma unroll
    for (int j = 0; j < 16; ++j){
      f32x4 v = *(const f32x4*)&cw[(qw + j) * 256 + (lane << 2)];
      u32x2 d = { pk2(v[0], v[1]), pk2(v[2], v[3]) };
      unsigned off = ((j << 9) + (lane << 3)) ^ ((j & 7) << 4);
      *(u32x2*)(reg + off) = d;
    }
    __syncthreads();
    #pragma unroll
    for (int nt = 0; nt < 16; ++nt){
      unsigned base = ((l15 << 9) + (nt << 5) + (g << 3)) ^ ((l15 & 7) << 4);
      cwp[nt][0] = *(const unsigned*)(reg + base);
      cwp[nt][1] = *(const unsigned*)(reg + base + 4);
      am[nt] = {0.f, 0.f, 0.f, 0.f};
    }
    __syncthreads();                              // K(0) certified; Vl free
  }

  for (int h = 0; h < 4; ++h){
    STG(Vl, Vf + ((size_t)(b * 4 + h) << 14));
    short8 qf0 = *(const short8*)&Qf[(((tileQ * 8 + (h << 1)) * 4 + wQ) * 64 + lane) * 8];
    short8 qf1 = *(const short8*)&Qf[(((tileQ * 8 + (h << 1) + 1) * 4 + wQ) * 64 + lane) * 8];

    f32x4 acc[16];
    #pragma unroll
    for (int nt = 0; nt < 16; ++nt) acc[nt] = {0.f, 0.f, 0.f, 0.f};
    __builtin_amdgcn_s_setprio(1);
    #pragma unroll
    for (int nt = 0; nt < 16; ++nt){
      short8 kf0 = *(const short8*)&Kl[(nt << 10) + (lane << 3)];
      acc[nt] = __builtin_amdgcn_mfma_f32_16x16x32_bf16(kf0, qf0, acc[nt], 0, 0, 0);
      short8 kf1 = *(const short8*)&Kl[(nt << 10) + 512 + (lane << 3)];
      acc[nt] = __builtin_amdgcn_mfma_f32_16x16x32_bf16(kf1, qf1, acc[nt], 0, 0, 0);
    }
    __builtin_amdgcn_s_setprio(0);
    __syncthreads();
    if (h < 3) STG(Kl, Kf + ((size_t)(b * 4 + h + 1) << 14));

    float mx = -3.4e38f;
    #pragma unroll
    for (int nt = 0; nt < 16; ++nt){
      float c0 = __uint_as_float(cwp[nt][0] << 16);
      float c1 = __uint_as_float(cwp[nt][0] & 0xffff0000u);
      float c2 = __uint_as_float(cwp[nt][1] << 16);
      float c3 = __uint_as_float(cwp[nt][1] & 0xffff0000u);
      acc[nt][0] = acc[nt][0] * 0.125f + c0;
      acc[nt][1] = acc[nt][1] * 0.125f + c1;
      acc[nt][2] = acc[nt][2] * 0.125f + c2;
      acc[nt][3] = acc[nt][3] * 0.125f + c3;
      mx = fmaxf(mx, fmaxf(fmaxf(acc[nt][0], acc[nt][1]), fmaxf(acc[nt][2], acc[nt][3])));
    }
    mx = fmaxf(mx, __shfl_xor(mx, 16));
    mx = fmaxf(mx, __shfl_xor(mx, 32));
    float sm = 0.f;
    #pragma unroll
    for (int nt = 0; nt < 16; ++nt){
      #pragma unroll
      for (int r = 0; r < 4; ++r){
        float e = __expf(acc[nt][r] - mx);
        acc[nt][r] = e; sm += e;
      }
    }
    sm += __shfl_xor(sm, 16);
    sm += __shfl_xor(sm, 32);
    float inv = 1.f / sm;
    #pragma unroll
    for (int nt = 0; nt < 16; ++nt){
      #pragma unroll
      for (int r = 0; r < 4; ++r){
        float p = acc[nt][r] * inv;
        acc[nt][r] = p;
        am[nt][r] += 0.25f * p;
      }
    }
    f32x4 oc[4] = {{0,0,0,0},{0,0,0,0},{0,0,0,0},{0,0,0,0}};
    __builtin_amdgcn_s_setprio(1);
    #pragma unroll
    for (int kk = 0; kk < 8; ++kk){
      union { short8 s; unsigned u[4]; } pa;
      pa.u[0] = pk2(acc[2 * kk][0],     acc[2 * kk][1]);
      pa.u[1] = pk2(acc[2 * kk][2],     acc[2 * kk][3]);
      pa.u[2] = pk2(acc[2 * kk + 1][0], acc[2 * kk + 1][1]);
      pa.u[3] = pk2(acc[2 * kk + 1][2], acc[2 * kk + 1][3]);
      #pragma unroll
      for (int n2 = 0; n2 < 4; ++n2){
        short8 vb = *(const short8*)&Vl[(((kk << 2) + n2) << 9) + (lane << 3)];
        oc[n2] = __builtin_amdgcn_mfma_f32_16x16x32_bf16(pa.s, vb, oc[n2], 0, 0, 0);
      }
    }
    __builtin_amdgcn_s_setprio(0);
    #pragma unroll
    for (int n2 = 0; n2 < 4; ++n2){
      const int sctx = (h << 1) + (n2 >> 1);
      const int gctx = ((n2 & 1) << 1) + (l15 >> 3);
      const int j = l15 & 7;
      #pragma unroll
      for (int r = 0; r < 4; ++r)
        ctx[(((tileC * 8 + sctx) * 4 + w) * 64 + (gctx << 4) + (g << 2) + r) * 8 + j]
            = f2b(oc[n2][r]);
    }
    __syncthreads();
  }

  {
    char* reg = (char*)smem + (w << 14);
    #pragma unroll
    for (int nt = 0; nt < 16; ++nt){
      unsigned off = ((l15 << 10) + (nt << 6) + (g << 4)) ^ ((l15 & 7) << 4);
      *(f32x4*)(reg + off) = am[nt];
    }
    __syncthreads();
    #pragma unroll
    for (int i2 = 0; i2 < 16; ++i2){
      unsigned fb = (tid << 4) + (i2 << 12);
      unsigned rowin = (fb >> 10) & 15;
      f32x4 v = *(const f32x4*)((char*)smem + (fb ^ ((rowin & 7) << 4)));
      unsigned row = fb >> 10;
      *(f32x4*)&am_out[((size_t)b * 4096 + q0 + row) * 256 + ((fb & 1023) >> 2)] = v;
    }
  }
#undef STG
}

// ---------------- fused tail, 8-wave N-split (r22, verbatim) ----------------
__global__ __launch_bounds__(512, 4) void tail_k(
    const short* __restrict__ ctxaf, const short* __restrict__ Wst,
    const float* __restrict__ b_o, const float* __restrict__ b_m1,
    const float* __restrict__ b_m2, const float* __restrict__ node,
    const float* __restrict__ lng, const float* __restrict__ lnb,
    float* __restrict__ outF)
{
  extern __shared__ __align__(16) short lds[];
  short* Ws0 = lds + 16896;
  short* Ws1 = Ws0 + 8192;
  float* part = (float*)(lds + 33280);
  const int tid = threadIdx.x;
  const int tile = blockIdx.x;
  const int m0 = tile << 6;
  const int w = tid >> 6, lane = tid & 63;
  const int l15 = lane & 15, g = lane >> 4;
  const int wm = w >> 1, wn = w & 1;
  const int row_l = (wm << 4) + (g << 2);
  const int colb = wn << 7;

#define ASW(row_, col_) (*(short*)((char*)lds + (row_) * 528 + \
    (((col_) ^ ((((row_) >> 2) & 3) << 3)) << 1)))
#define ASR8(row_, boff_) (*(const short8*)((char*)lds + (row_) * 528 + \
    ((boff_) ^ ((((row_) >> 2) & 3) << 4))))
#define STGW(dst_, wmat_, s_) do{ _Pragma("unroll")                                  \
  for (int it_ = 0; it_ < 2; ++it_){ int c_ = (it_ << 9) + tid;                      \
    __builtin_amdgcn_global_load_lds(                                               \
        (const AS1 void*)((wmat_) + ((size_t)(s_) << 13) + (c_ << 3)),              \
        (AS3 void*)((dst_) + (c_ << 3)), 16, 0, 0); } }while(0)
#define KLOOP(WMAT, AF_EXPR)                                                         \
  do{ int cur = 0;                                                                   \
    _Pragma("unroll")                                                                \
    for (int s = 0; s < 8; ++s){                                                     \
      short* rbuf = cur ? Ws1 : Ws0;                                                 \
      short* sbuf = cur ? Ws0 : Ws1;                                                 \
      if (s < 7){ STGW(sbuf, WMAT, s + 1);                                           \
        asm volatile("s_waitcnt vmcnt(2)" ::: "memory");                             \
      } else {                                                                       \
        asm volatile("s_waitcnt vmcnt(0)" ::: "memory");                             \
      }                                                                              \
      __builtin_amdgcn_s_barrier();                                                  \
      __builtin_amdgcn_sched_barrier(0);                                             \
      const short8 af = (AF_EXPR);                                                   \
      __builtin_amdgcn_s_setprio(1);                                                 \
      _Pragma("unroll")                                                              \
      for (int ntl = 0; ntl < 8; ++ntl){                                             \
        short8 bf = *(const short8*)&rbuf[(((wn << 3) + ntl) * 16 + l15) * 32 + (g << 3)]; \
        acc[ntl] = __builtin_amdgcn_mfma_f32_16x16x32_bf16(af, bf, acc[ntl], 0, 0, 0); \
      }                                                                              \
      __builtin_amdgcn_s_setprio(0);                                                 \
      __builtin_amdgcn_s_barrier();                                                  \
      __builtin_amdgcn_sched_barrier(0);                                             \
      cur ^= 1;                                                                      \
    } }while(0)

  f32x4 acc[8];

  STGW(Ws0, Wst, 0);
  short8 afr[8];
  #pragma unroll
  for (int s = 0; s < 8; ++s)
    afr[s] = *(const short8*)&ctxaf[((((size_t)tile << 3) + s) * 4 + wm) * 512 + (lane << 3)];
  #pragma unroll
  for (int ntl = 0; ntl < 8; ++ntl) acc[ntl] = {0.f, 0.f, 0.f, 0.f};
  KLOOP(Wst, afr[s]);

  unsigned xvp[8][2];
  #pragma unroll
  for (int ntl = 0; ntl < 8; ++ntl){
    const int col = colb + (ntl << 4) + l15;
    const float bv = b_o[col];
    float x0 = acc[ntl][0] + bv + node[(size_t)(m0 + row_l + 0) * 256 + col];
    float x1 = acc[ntl][1] + bv + node[(size_t)(m0 + row_l + 1) * 256 + col];
    float x2 = acc[ntl][2] + bv + node[(size_t)(m0 + row_l + 2) * 256 + col];
    float x3 = acc[ntl][3] + bv + node[(size_t)(m0 + row_l + 3) * 256 + col];
    xvp[ntl][0] = pk2(x0, x1);
    xvp[ntl][1] = pk2(x2, x3);
  }
  #pragma unroll
  for (int r = 0; r < 4; ++r){
    float s1 = 0.f, s2 = 0.f;
    #pragma unroll
    for (int ntl = 0; ntl < 8; ++ntl){
      float v = (r == 0) ? ulo(xvp[ntl][0]) : (r == 1) ? uhi(xvp[ntl][0])
              : (r == 2) ? ulo(xvp[ntl][1]) : uhi(xvp[ntl][1]);
      s1 += v; s2 += v * v;
    }
    #pragma unroll
    for (int off = 1; off < 16; off <<= 1){ s1 += __shfl_xor(s1, off); s2 += __shfl_xor(s2, off); }
    if (l15 == 0){
      part[((row_l + r) * 2 + wn) * 2]     = s1;
      part[((row_l + r) * 2 + wn) * 2 + 1] = s2;
    }
  }
  __syncthreads();
  #pragma unroll
  for (int r = 0; r < 4; ++r){
    const int row = row_l + r;
    const float S1 = part[(row * 2) * 2]     + part[(row * 2 + 1) * 2];
    const float S2 = part[(row * 2) * 2 + 1] + part[(row * 2 + 1) * 2 + 1];
    const float mu = S1 * 0.00390625f;
    const float rs = rsqrtf(S2 * 0.00390625f - mu * mu + 1e-5f);
    #pragma unroll
    for (int ntl = 0; ntl < 8; ++ntl){
      const int col = colb + (ntl << 4) + l15;
      float v = (r == 0) ? ulo(xvp[ntl][0]) : (r == 1) ? uhi(xvp[ntl][0])
              : (r == 2) ? ulo(xvp[ntl][1]) : uhi(xvp[ntl][1]);
      ASW(row, col) = f2b((v - mu) * rs * lng[col] + lnb[col]);
    }
  }

  {
    const short* Wm1 = Wst + 65536;
    STGW(Ws0, Wm1, 0);
    __syncthreads();
    #pragma unroll
    for (int ntl = 0; ntl < 8; ++ntl) acc[ntl] = {0.f, 0.f, 0.f, 0.f};
    KLOOP(Wm1, ASR8((wm << 4) + l15, (s << 6) + (g << 4)));
  }
  #pragma unroll
  for (int ntl = 0; ntl < 8; ++ntl){
    const int col = colb + (ntl << 4) + l15;
    const float bv = b_m1[col];
    #pragma unroll
    for (int r = 0; r < 4; ++r){
      float v = acc[ntl][r] + bv;
      v = 0.5f * v * (1.0f + erff(v * 0.70710678118f));
      ASW(row_l + r, col) = f2b(v);
    }
  }

  {
    const short* Wm2 = Wst + 131072;
    STGW(Ws0, Wm2, 0);
    __syncthreads();
    #pragma unroll
    for (int ntl = 0; ntl < 8; ++ntl) acc[ntl] = {0.f, 0.f, 0.f, 0.f};
    KLOOP(Wm2, ASR8((wm << 4) + l15, (s << 6) + (g << 4)));
  }
  #pragma unroll
  for (int ntl = 0; ntl < 8; ++ntl){
    const int col = colb + (ntl << 4) + l15;
    const float bv = b_m2[col];
    #pragma unroll
    for (int r = 0; r < 4; ++r){
      float xr = (r == 0) ? ulo(xvp[ntl][0]) : (r == 1) ? uhi(xvp[ntl][0])
               : (r == 2) ? ulo(xvp[ntl][1]) : uhi(xvp[ntl][1]);
      outF[(size_t)(m0 + row_l + r) * 256 + col] = acc[ntl][r] + bv + xr;
    }
  }
#undef ASW
#undef ASR8
#undef STGW
#undef KLOOP
}

extern "C" void kernel_launch(void* const* d_in, const int* in_sizes, int n_in,
                              void* d_out, int out_size, void* d_ws, size_t ws_size,
                              hipStream_t stream)
{
  const float* node_emb = (const float*)d_in[0];
  const float* cluster  = (const float*)d_in[1];
  const float* cw       = (const float*)d_in[2];
  const float* ln_q_g   = (const float*)d_in[3];
  const float* ln_q_b   = (const float*)d_in[4];
  const float* ln_kv_g  = (const float*)d_in[5];
  const float* ln_kv_b  = (const float*)d_in[6];
  const float* ln_o_g   = (const float*)d_in[7];
  const float* ln_o_b   = (const float*)d_in[8];
  const float* W_q  = (const float*)d_in[9];  const float* b_q  = (const float*)d_in[10];
  const float* W_k  = (const float*)d_in[11]; const float* b_k  = (const float*)d_in[12];
  const float* W_v  = (const float*)d_in[13]; const float* b_v  = (const float*)d_in[14];
  const float* W_o  = (const float*)d_in[15]; const float* b_o  = (const float*)d_in[16];
  const float* W_m1 = (const float*)d_in[17]; const float* b_m1 = (const float*)d_in[18];
  const float* W_m2 = (const float*)d_in[19]; const float* b_m2 = (const float*)d_in[20];

  char* ws = (char*)d_ws;
  short* Wbf   = (short*)ws;                                   // 786,432 B row-major (6 mats)
  short* Wst   = (short*)(ws + 786432);                        // 524,288 B stage-order (O,M1,M2,Q)
  short* bufA  = (short*)(ws + 1310720);                       // 16.78 MB: ctx afrag
  short* bufB  = (short*)(ws + 1310720 + 16777216);            // 16.78 MB: Q afrag
  short* kfrag = (short*)(ws + 1310720 + 2 * 16777216);
  short* vfrag = (short*)(ws + 1310720 + 2 * 16777216 + 1048576);

  float* outF = (float*)d_out;            // final out (written only by tail_k)
  float* amof = (float*)d_out + 8388608;  // attn_matrix

  hipFuncSetAttribute((const void*)attn_k,  hipFuncAttributeMaxDynamicSharedMemorySize, 65536);
  hipFuncSetAttribute((const void*)tail_k,  hipFuncAttributeMaxDynamicSharedMemorySize, 67584);
  hipFuncSetAttribute((const void*)qgemm_k, hipFuncAttributeMaxDynamicSharedMemorySize, 66560);

  cvt_w<<<1536, 256, 0, stream>>>(W_q, W_k, W_v, W_o, W_m1, W_m2, Wbf, Wst);
  // fused K+V projection (LN(cluster) once) -> kfrag / vfrag
  kv_k<<<32, 256, 0, stream>>>(cluster, Wbf + 65536, Wbf + 131072,
      b_k, b_v, ln_kv_g, ln_kv_b, kfrag, vfrag);
  // Q projection: 8-wave, fused input-LN, afrag output -> bufB
  qgemm_k<<<512, 512, 66560, stream>>>(node_emb, Wst + 196608, b_q,
      ln_q_g, ln_q_b, bufB);
  // attention (ctx afrag -> bufA, attn_matrix -> d_out 2nd half)
  attn_k<<<dim3(64, 8), 256, 65536, stream>>>(bufB, kfrag, vfrag, cw, bufA, amof);
  // fused tail: O(+res)+LN -> M1(+GELU) -> M2(+res) -> out (8-wave blocks)
  tail_k<<<512, 512, 67584, stream>>>(bufA, Wst, b_o, b_m1, b_m2,
      node_emb, ln_o_g, ln_o_b, outF);
}

// Round 25
// 104.496 us; speedup vs baseline: 1.2765x; 1.1051x over previous
//
#include <hip/hip_runtime.h>
#include <math.h>

typedef __attribute__((ext_vector_type(8))) short short8;
typedef __attribute__((ext_vector_type(4))) float f32x4;
typedef __attribute__((ext_vector_type(2))) unsigned int u32x2;

#define AS1 __attribute__((address_space(1)))
#define AS3 __attribute__((address_space(3)))

__device__ __forceinline__ float b2f(short s){
  return __uint_as_float(((unsigned int)(unsigned short)s) << 16);
}
__device__ __forceinline__ short f2b(float f){
  unsigned int u = __float_as_uint(f);
  u = (u + 0x7fffu + ((u >> 16) & 1u)) >> 16;
  return (short)u;
}
__device__ __forceinline__ unsigned pk2(float lo, float hi){
  return ((unsigned)(unsigned short)f2b(hi) << 16) | (unsigned)(unsigned short)f2b(lo);
}
__device__ __forceinline__ float ulo(unsigned u){ return __uint_as_float(u << 16); }
__device__ __forceinline__ float uhi(unsigned u){ return __uint_as_float(u & 0xffff0000u); }

// ---------------- weight f32 -> bf16, stage-order only ----------------
// dstS slots: {0:W_o, 1:W_m1, 2:W_m2, 3:W_q, 4:W_k, 5:W_v} = (mat+3)%6.
__global__ __launch_bounds__(256) void cvt_w(
    const float* __restrict__ s0, const float* __restrict__ s1,
    const float* __restrict__ s2, const float* __restrict__ s3,
    const float* __restrict__ s4, const float* __restrict__ s5,
    short* __restrict__ dstS)
{
  const float* srcs[6] = {s0, s1, s2, s3, s4, s5};
  int i = blockIdx.x * 256 + threadIdx.x;       // 6*65536 total
  int mat = i >> 16, rc = i & 65535;
  short v = f2b(srcs[mat][rc]);
  int slot = (mat + 3) % 6;
  int row = rc >> 8, col = rc & 255;
  int d2 = slot * 65536 + ((col >> 5) << 13) + (row << 5)
         + (((col >> 3) & 3) << 3) + (col & 7);
  dstS[d2] = v;
}

// -------- fused Q + K + V projections, one dispatch --------------------------
// Blocks 0..31: KV path (LN(cluster) once, K-KLOOP -> kfrag, V-KLOOP -> vfrag).
// Blocks 32..543: Q path (LN(node) -> swizzled As, KLOOP(W_q) -> afrag).
// KV blocks FIRST so their 2x-longer bodies start in scheduling round 1.
__global__ __launch_bounds__(512, 4) void qkv_k(
    const float* __restrict__ node, const float* __restrict__ cluster,
    const short* __restrict__ Wst,
    const float* __restrict__ b_q, const float* __restrict__ b_k,
    const float* __restrict__ b_v,
    const float* __restrict__ lnqg, const float* __restrict__ lnqb,
    const float* __restrict__ lnkg, const float* __restrict__ lnkb,
    short* __restrict__ qaf, short* __restrict__ kfrag, short* __restrict__ vfrag)
{
  extern __shared__ __align__(16) short lds[];
  short* Ws0 = lds + 16896;              // As: [0, 33792) bytes
  short* Ws1 = Ws0 + 8192;               // Ws: 2 x 16384 B
  const int tid = threadIdx.x;
  const int w = tid >> 6, lane = tid & 63;
  const int l15 = lane & 15, g = lane >> 4;
  const int wm = w >> 1, wn = w & 1;
  const int row_l = (wm << 4) + (g << 2);
  const int colb = wn << 7;
  const int isKV = (blockIdx.x < 32);
  const int tile = isKV ? blockIdx.x : (blockIdx.x - 32);
  const int m0 = tile << 6;

#define ASW8(row_, col0_) (*(short8*)((char*)lds + (row_) * 528 + \
    (((col0_) << 1) ^ ((((row_) >> 2) & 3) << 4))))
#define ASR8(row_, boff_) (*(const short8*)((char*)lds + (row_) * 528 + \
    ((boff_) ^ ((((row_) >> 2) & 3) << 4))))
#define STGW(dst_, wmat_, s_) do{ _Pragma("unroll")                                  \
  for (int it_ = 0; it_ < 2; ++it_){ int c_ = (it_ << 9) + tid;                      \
    __builtin_amdgcn_global_load_lds(                                               \
        (const AS1 void*)((wmat_) + ((size_t)(s_) << 13) + (c_ << 3)),              \
        (AS3 void*)((dst_) + (c_ << 3)), 16, 0, 0); } }while(0)
#define KLOOP(WMAT)                                                                  \
  do{ int cur = 0;                                                                   \
    _Pragma("unroll")                                                                \
    for (int s = 0; s < 8; ++s){                                                     \
      short* rbuf = cur ? Ws1 : Ws0;                                                 \
      short* sbuf = cur ? Ws0 : Ws1;                                                 \
      if (s < 7){ STGW(sbuf, WMAT, s + 1);                                           \
        asm volatile("s_waitcnt vmcnt(2)" ::: "memory");                             \
      } else {                                                                       \
        asm volatile("s_waitcnt vmcnt(0)" ::: "memory");                             \
      }                                                                              \
      __builtin_amdgcn_s_barrier();                                                  \
      __builtin_amdgcn_sched_barrier(0);                                             \
      const short8 af = ASR8((wm << 4) + l15, (s << 6) + (g << 4));                  \
      __builtin_amdgcn_s_setprio(1);                                                 \
      _Pragma("unroll")                                                              \
      for (int ntl = 0; ntl < 8; ++ntl){                                             \
        short8 bf = *(const short8*)&rbuf[(((wn << 3) + ntl) * 16 + l15) * 32 + (g << 3)]; \
        acc[ntl] = __builtin_amdgcn_mfma_f32_16x16x32_bf16(af, bf, acc[ntl], 0, 0, 0); \
      }                                                                              \
      __builtin_amdgcn_s_setprio(0);                                                 \
      __builtin_amdgcn_s_barrier();                                                  \
      __builtin_amdgcn_sched_barrier(0);                                             \
      cur ^= 1;                                                                      \
    } }while(0)

  // ---- LN prologue: 8 thr/row, 32 cols each -> swizzled As ----
  {
    const float* srcb = isKV ? cluster : node;
    const float* lg = isKV ? lnkg : lnqg;
    const float* lb = isKV ? lnkb : lnqb;
    const int row = tid >> 3, c0 = (tid & 7) << 5;
    float vv[32];
    const float* src = &srcb[(size_t)(m0 + row) * 256 + c0];
    #pragma unroll
    for (int i = 0; i < 8; ++i) *(f32x4*)&vv[4 * i] = *(const f32x4*)&src[4 * i];
    float s1 = 0.f, s2 = 0.f;
    #pragma unroll
    for (int i = 0; i < 32; ++i){ s1 += vv[i]; s2 += vv[i] * vv[i]; }
    s1 += __shfl_xor(s1, 1); s2 += __shfl_xor(s2, 1);
    s1 += __shfl_xor(s1, 2); s2 += __shfl_xor(s2, 2);
    s1 += __shfl_xor(s1, 4); s2 += __shfl_xor(s2, 4);
    const float mu = s1 * 0.00390625f;
    const float rs = rsqrtf(s2 * 0.00390625f - mu * mu + 1e-5f);
    #pragma unroll
    for (int i = 0; i < 4; ++i){
      const int col0 = c0 + 8 * i;
      f32x4 g0 = *(const f32x4*)&lg[col0], g1 = *(const f32x4*)&lg[col0 + 4];
      f32x4 b0 = *(const f32x4*)&lb[col0], b1 = *(const f32x4*)&lb[col0 + 4];
      short8 o;
      #pragma unroll
      for (int j = 0; j < 4; ++j) o[j] = f2b((vv[8 * i + j] - mu) * rs * g0[j] + b0[j]);
      #pragma unroll
      for (int j = 0; j < 4; ++j) o[4 + j] = f2b((vv[8 * i + 4 + j] - mu) * rs * g1[j] + b1[j]);
      ASW8(row, col0) = o;
    }
  }

  f32x4 acc[8];

  if (!isKV){
    // ================= Q path =================
    const short* Wq = Wst + 196608;     // slot 3
    STGW(Ws0, Wq, 0);
    __syncthreads();
    #pragma unroll
    for (int ntl = 0; ntl < 8; ++ntl) acc[ntl] = {0.f, 0.f, 0.f, 0.f};
    KLOOP(Wq);
    #pragma unroll
    for (int ntl = 0; ntl < 8; ++ntl){
      const int col = colb + (ntl << 4) + l15;
      const float bv = b_q[col];
      #pragma unroll
      for (int r = 0; r < 4; ++r){
        float v = acc[ntl][r] + bv;
        qaf[((((size_t)tile * 8 + (col >> 5)) * 4 + wm) * 64
              + (((col >> 3) & 3) << 4) + (g << 2) + r) * 8 + (col & 7)] = f2b(v);
      }
    }
  } else {
    // ================= KV path =================
    const short* Wk = Wst + 262144;     // slot 4
    const short* Wv = Wst + 327680;     // slot 5
    STGW(Ws0, Wk, 0);
    __syncthreads();
    #pragma unroll
    for (int ntl = 0; ntl < 8; ++ntl) acc[ntl] = {0.f, 0.f, 0.f, 0.f};
    KLOOP(Wk);
    #pragma unroll
    for (int ntl = 0; ntl < 8; ++ntl){
      const int col = colb + (ntl << 4) + l15;
      const float bv = b_k[col];
      const int h = col >> 6, half = (col >> 5) & 1, kg = (col >> 3) & 3, kj = col & 7;
      #pragma unroll
      for (int r = 0; r < 4; ++r){
        const int m = m0 + row_l + r;
        float v = acc[ntl][r] + bv;
        const int b_ = m >> 8, kvr = m & 255;
        const int knt = kvr >> 4, kl = kvr & 15;
        kfrag[(((((size_t)(b_ * 4 + h) * 16 + knt) * 2 + half) * 4 + kg) * 16 + kl) * 8 + kj] = f2b(v);
      }
    }
    // V pass: As unchanged; Ws0 free after the K loop's final barrier+vmcnt(0)
    STGW(Ws0, Wv, 0);
    __syncthreads();
    #pragma unroll
    for (int ntl = 0; ntl < 8; ++ntl) acc[ntl] = {0.f, 0.f, 0.f, 0.f};
    KLOOP(Wv);
    #pragma unroll
    for (int ntl = 0; ntl < 8; ++ntl){
      const int col = colb + (ntl << 4) + l15;
      const float bv = b_v[col];
      const int h = col >> 6, dp = col & 63;
      const int vn2 = dp >> 4, vl = dp & 15;
      #pragma unroll
      for (int r = 0; r < 4; ++r){
        const int m = m0 + row_l + r;
        float v = acc[ntl][r] + bv;
        const int b_ = m >> 8, kvj = m & 255;
        const int jp = (kvj & ~31) | (((kvj >> 2) & 3) << 3) | (((kvj >> 4) & 1) << 2) | (kvj & 3);
        const int kk = jp >> 5, vg = (jp >> 3) & 3, vj = jp & 7;
        vfrag[(((((size_t)(b_ * 4 + h) * 8 + kk) * 4 + vn2) * 4 + vg) * 16 + vl) * 8 + vj] = f2b(v);
      }
    }
  }
#undef ASW8
#undef ASR8
#undef STGW
#undef KLOOP
}

// ---------------- fused MFMA attention (r22 proven, verbatim) ---------------
__global__ __launch_bounds__(256, 2) void attn_k(
    const short* __restrict__ Qf, const short* __restrict__ Kf,
    const short* __restrict__ Vf, const float* __restrict__ cw,
    short* __restrict__ ctx, float* __restrict__ am_out)
{
  extern __shared__ __align__(16) short smem[];   // 32768 shorts = 64KB
  short* Kl = smem;
  short* Vl = smem + 16384;
  const int b = blockIdx.y;
  const int q0 = blockIdx.x << 6;
  const int tid = threadIdx.x;
  const int w = tid >> 6, lane = tid & 63;
  const int l15 = lane & 15, g = lane >> 4;
  const size_t qw = (size_t)b * 4096 + q0 + (w << 4);
  const size_t qblk = qw >> 4;
  const size_t tileQ = qblk >> 2;
  const int wQ = (int)(qblk & 3);
  const size_t tileC = (size_t)b * 64 + blockIdx.x;

#define STG(dst_, src_) do{ _Pragma("unroll")                                        \
  for (int it_ = 0; it_ < 8; ++it_){ int c_ = (it_ << 8) + tid;                      \
    __builtin_amdgcn_global_load_lds((const AS1 void*)((src_) + (c_ << 3)),          \
                                     (AS3 void*)((dst_) + (c_ << 3)), 16, 0, 0); } }while(0)

  STG(Kl, Kf + ((size_t)(b * 4) << 14));          // K(0) overlaps the cw phase

  unsigned cwp[16][2];
  f32x4 am[16];
  {
    char* reg = (char*)smem + 32768 + (w << 13);  // bounce scratch in Vl region
    #pragma unroll
    for (int j = 0; j < 16; ++j){
      f32x4 v = *(const f32x4*)&cw[(qw + j) * 256 + (lane << 2)];
      u32x2 d = { pk2(v[0], v[1]), pk2(v[2], v[3]) };
      unsigned off = ((j << 9) + (lane << 3)) ^ ((j & 7) << 4);
      *(u32x2*)(reg + off) = d;
    }
    __syncthreads();
    #pragma unroll
    for (int nt = 0; nt < 16; ++nt){
      unsigned base = ((l15 << 9) + (nt << 5) + (g << 3)) ^ ((l15 & 7) << 4);
      cwp[nt][0] = *(const unsigned*)(reg + base);
      cwp[nt][1] = *(const unsigned*)(reg + base + 4);
      am[nt] = {0.f, 0.f, 0.f, 0.f};
    }
    __syncthreads();                              // K(0) certified; Vl free
  }

  for (int h = 0; h < 4; ++h){
    STG(Vl, Vf + ((size_t)(b * 4 + h) << 14));
    short8 qf0 = *(const short8*)&Qf[(((tileQ * 8 + (h << 1)) * 4 + wQ) * 64 + lane) * 8];
    short8 qf1 = *(const short8*)&Qf[(((tileQ * 8 + (h << 1) + 1) * 4 + wQ) * 64 + lane) * 8];

    f32x4 acc[16];
    #pragma unroll
    for (int nt = 0; nt < 16; ++nt) acc[nt] = {0.f, 0.f, 0.f, 0.f};
    __builtin_amdgcn_s_setprio(1);
    #pragma unroll
    for (int nt = 0; nt < 16; ++nt){
      short8 kf0 = *(const short8*)&Kl[(nt << 10) + (lane << 3)];
      acc[nt] = __builtin_amdgcn_mfma_f32_16x16x32_bf16(kf0, qf0, acc[nt], 0, 0, 0);
      short8 kf1 = *(const short8*)&Kl[(nt << 10) + 512 + (lane << 3)];
      acc[nt] = __builtin_amdgcn_mfma_f32_16x16x32_bf16(kf1, qf1, acc[nt], 0, 0, 0);
    }
    __builtin_amdgcn_s_setprio(0);
    __syncthreads();
    if (h < 3) STG(Kl, Kf + ((size_t)(b * 4 + h + 1) << 14));

    float mx = -3.4e38f;
    #pragma unroll
    for (int nt = 0; nt < 16; ++nt){
      float c0 = __uint_as_float(cwp[nt][0] << 16);
      float c1 = __uint_as_float(cwp[nt][0] & 0xffff0000u);
      float c2 = __uint_as_float(cwp[nt][1] << 16);
      float c3 = __uint_as_float(cwp[nt][1] & 0xffff0000u);
      acc[nt][0] = acc[nt][0] * 0.125f + c0;
      acc[nt][1] = acc[nt][1] * 0.125f + c1;
      acc[nt][2] = acc[nt][2] * 0.125f + c2;
      acc[nt][3] = acc[nt][3] * 0.125f + c3;
      mx = fmaxf(mx, fmaxf(fmaxf(acc[nt][0], acc[nt][1]), fmaxf(acc[nt][2], acc[nt][3])));
    }
    mx = fmaxf(mx, __shfl_xor(mx, 16));
    mx = fmaxf(mx, __shfl_xor(mx, 32));
    float sm = 0.f;
    #pragma unroll
    for (int nt = 0; nt < 16; ++nt){
      #pragma unroll
      for (int r = 0; r < 4; ++r){
        float e = __expf(acc[nt][r] - mx);
        acc[nt][r] = e; sm += e;
      }
    }
    sm += __shfl_xor(sm, 16);
    sm += __shfl_xor(sm, 32);
    float inv = 1.f / sm;
    #pragma unroll
    for (int nt = 0; nt < 16; ++nt){
      #pragma unroll
      for (int r = 0; r < 4; ++r){
        float p = acc[nt][r] * inv;
        acc[nt][r] = p;
        am[nt][r] += 0.25f * p;
      }
    }
    f32x4 oc[4] = {{0,0,0,0},{0,0,0,0},{0,0,0,0},{0,0,0,0}};
    __builtin_amdgcn_s_setprio(1);
    #pragma unroll
    for (int kk = 0; kk < 8; ++kk){
      union { short8 s; unsigned u[4]; } pa;
      pa.u[0] = pk2(acc[2 * kk][0],     acc[2 * kk][1]);
      pa.u[1] = pk2(acc[2 * kk][2],     acc[2 * kk][3]);
      pa.u[2] = pk2(acc[2 * kk + 1][0], acc[2 * kk + 1][1]);
      pa.u[3] = pk2(acc[2 * kk + 1][2], acc[2 * kk + 1][3]);
      #pragma unroll
      for (int n2 = 0; n2 < 4; ++n2){
        short8 vb = *(const short8*)&Vl[(((kk << 2) + n2) << 9) + (lane << 3)];
        oc[n2] = __builtin_amdgcn_mfma_f32_16x16x32_bf16(pa.s, vb, oc[n2], 0, 0, 0);
      }
    }
    __builtin_amdgcn_s_setprio(0);
    #pragma unroll
    for (int n2 = 0; n2 < 4; ++n2){
      const int sctx = (h << 1) + (n2 >> 1);
      const int gctx = ((n2 & 1) << 1) + (l15 >> 3);
      const int j = l15 & 7;
      #pragma unroll
      for (int r = 0; r < 4; ++r)
        ctx[(((tileC * 8 + sctx) * 4 + w) * 64 + (gctx << 4) + (g << 2) + r) * 8 + j]
            = f2b(oc[n2][r]);
    }
    __syncthreads();
  }

  {
    char* reg = (char*)smem + (w << 14);
    #pragma unroll
    for (int nt = 0; nt < 16; ++nt){
      unsigned off = ((l15 << 10) + (nt << 6) + (g << 4)) ^ ((l15 & 7) << 4);
      *(f32x4*)(reg + off) = am[nt];
    }
    __syncthreads();
    #pragma unroll
    for (int i2 = 0; i2 < 16; ++i2){
      unsigned fb = (tid << 4) + (i2 << 12);
      unsigned rowin = (fb >> 10) & 15;
      f32x4 v = *(const f32x4*)((char*)smem + (fb ^ ((rowin & 7) << 4)));
      unsigned row = fb >> 10;
      *(f32x4*)&am_out[((size_t)b * 4096 + q0 + row) * 256 + ((fb & 1023) >> 2)] = v;
    }
  }
#undef STG
}

// ---------------- fused tail, 8-wave N-split (r22, verbatim) ----------------
__global__ __launch_bounds__(512, 4) void tail_k(
    const short* __restrict__ ctxaf, const short* __restrict__ Wst,
    const float* __restrict__ b_o, const float* __restrict__ b_m1,
    const float* __restrict__ b_m2, const float* __restrict__ node,
    const float* __restrict__ lng, const float* __restrict__ lnb,
    float* __restrict__ outF)
{
  extern __shared__ __align__(16) short lds[];
  short* Ws0 = lds + 16896;
  short* Ws1 = Ws0 + 8192;
  float* part = (float*)(lds + 33280);
  const int tid = threadIdx.x;
  const int tile = blockIdx.x;
  const int m0 = tile << 6;
  const int w = tid >> 6, lane = tid & 63;
  const int l15 = lane & 15, g = lane >> 4;
  const int wm = w >> 1, wn = w & 1;
  const int row_l = (wm << 4) + (g << 2);
  const int colb = wn << 7;

#define ASW(row_, col_) (*(short*)((char*)lds + (row_) * 528 + \
    (((col_) ^ ((((row_) >> 2) & 3) << 3)) << 1)))
#define ASR8(row_, boff_) (*(const short8*)((char*)lds + (row_) * 528 + \
    ((boff_) ^ ((((row_) >> 2) & 3) << 4))))
#define STGW(dst_, wmat_, s_) do{ _Pragma("unroll")                                  \
  for (int it_ = 0; it_ < 2; ++it_){ int c_ = (it_ << 9) + tid;                      \
    __builtin_amdgcn_global_load_lds(                                               \
        (const AS1 void*)((wmat_) + ((size_t)(s_) << 13) + (c_ << 3)),              \
        (AS3 void*)((dst_) + (c_ << 3)), 16, 0, 0); } }while(0)
#define KLOOP(WMAT, AF_EXPR)                                                         \
  do{ int cur = 0;                                                                   \
    _Pragma("unroll")                                                                \
    for (int s = 0; s < 8; ++s){                                                     \
      short* rbuf = cur ? Ws1 : Ws0;                                                 \
      short* sbuf = cur ? Ws0 : Ws1;                                                 \
      if (s < 7){ STGW(sbuf, WMAT, s + 1);                                           \
        asm volatile("s_waitcnt vmcnt(2)" ::: "memory");                             \
      } else {                                                                       \
        asm volatile("s_waitcnt vmcnt(0)" ::: "memory");                             \
      }                                                                              \
      __builtin_amdgcn_s_barrier();                                                  \
      __builtin_amdgcn_sched_barrier(0);                                             \
      const short8 af = (AF_EXPR);                                                   \
      __builtin_amdgcn_s_setprio(1);                                                 \
      _Pragma("unroll")                                                              \
      for (int ntl = 0; ntl < 8; ++ntl){                                             \
        short8 bf = *(const short8*)&rbuf[(((wn << 3) + ntl) * 16 + l15) * 32 + (g << 3)]; \
        acc[ntl] = __builtin_amdgcn_mfma_f32_16x16x32_bf16(af, bf, acc[ntl], 0, 0, 0); \
      }                                                                              \
      __builtin_amdgcn_s_setprio(0);                                                 \
      __builtin_amdgcn_s_barrier();                                                  \
      __builtin_amdgcn_sched_barrier(0);                                             \
      cur ^= 1;                                                                      \
    } }while(0)

  f32x4 acc[8];

  STGW(Ws0, Wst, 0);
  short8 afr[8];
  #pragma unroll
  for (int s = 0; s < 8; ++s)
    afr[s] = *(const short8*)&ctxaf[((((size_t)tile << 3) + s) * 4 + wm) * 512 + (lane << 3)];
  #pragma unroll
  for (int ntl = 0; ntl < 8; ++ntl) acc[ntl] = {0.f, 0.f, 0.f, 0.f};
  KLOOP(Wst, afr[s]);

  unsigned xvp[8][2];
  #pragma unroll
  for (int ntl = 0; ntl < 8; ++ntl){
    const int col = colb + (ntl << 4) + l15;
    const float bv = b_o[col];
    float x0 = acc[ntl][0] + bv + node[(size_t)(m0 + row_l + 0) * 256 + col];
    float x1 = acc[ntl][1] + bv + node[(size_t)(m0 + row_l + 1) * 256 + col];
    float x2 = acc[ntl][2] + bv + node[(size_t)(m0 + row_l + 2) * 256 + col];
    float x3 = acc[ntl][3] + bv + node[(size_t)(m0 + row_l + 3) * 256 + col];
    xvp[ntl][0] = pk2(x0, x1);
    xvp[ntl][1] = pk2(x2, x3);
  }
  #pragma unroll
  for (int r = 0; r < 4; ++r){
    float s1 = 0.f, s2 = 0.f;
    #pragma unroll
    for (int ntl = 0; ntl < 8; ++ntl){
      float v = (r == 0) ? ulo(xvp[ntl][0]) : (r == 1) ? uhi(xvp[ntl][0])
              : (r == 2) ? ulo(xvp[ntl][1]) : uhi(xvp[ntl][1]);
      s1 += v; s2 += v * v;
    }
    #pragma unroll
    for (int off = 1; off < 16; off <<= 1){ s1 += __shfl_xor(s1, off); s2 += __shfl_xor(s2, off); }
    if (l15 == 0){
      part[((row_l + r) * 2 + wn) * 2]     = s1;
      part[((row_l + r) * 2 + wn) * 2 + 1] = s2;
    }
  }
  __syncthreads();
  #pragma unroll
  for (int r = 0; r < 4; ++r){
    const int row = row_l + r;
    const float S1 = part[(row * 2) * 2]     + part[(row * 2 + 1) * 2];
    const float S2 = part[(row * 2) * 2 + 1] + part[(row * 2 + 1) * 2 + 1];
    const float mu = S1 * 0.00390625f;
    const float rs = rsqrtf(S2 * 0.00390625f - mu * mu + 1e-5f);
    #pragma unroll
    for (int ntl = 0; ntl < 8; ++ntl){
      const int col = colb + (ntl << 4) + l15;
      float v = (r == 0) ? ulo(xvp[ntl][0]) : (r == 1) ? uhi(xvp[ntl][0])
              : (r == 2) ? ulo(xvp[ntl][1]) : uhi(xvp[ntl][1]);
      ASW(row, col) = f2b((v - mu) * rs * lng[col] + lnb[col]);
    }
  }

  {
    const short* Wm1 = Wst + 65536;
    STGW(Ws0, Wm1, 0);
    __syncthreads();
    #pragma unroll
    for (int ntl = 0; ntl < 8; ++ntl) acc[ntl] = {0.f, 0.f, 0.f, 0.f};
    KLOOP(Wm1, ASR8((wm << 4) + l15, (s << 6) + (g << 4)));
  }
  #pragma unroll
  for (int ntl = 0; ntl < 8; ++ntl){
    const int col = colb + (ntl << 4) + l15;
    const float bv = b_m1[col];
    #pragma unroll
    for (int r = 0; r < 4; ++r){
      float v = acc[ntl][r] + bv;
      v = 0.5f * v * (1.0f + erff(v * 0.70710678118f));
      ASW(row_l + r, col) = f2b(v);
    }
  }

  {
    const short* Wm2 = Wst + 131072;
    STGW(Ws0, Wm2, 0);
    __syncthreads();
    #pragma unroll
    for (int ntl = 0; ntl < 8; ++ntl) acc[ntl] = {0.f, 0.f, 0.f, 0.f};
    KLOOP(Wm2, ASR8((wm << 4) + l15, (s << 6) + (g << 4)));
  }
  #pragma unroll
  for (int ntl = 0; ntl < 8; ++ntl){
    const int col = colb + (ntl << 4) + l15;
    const float bv = b_m2[col];
    #pragma unroll
    for (int r = 0; r < 4; ++r){
      float xr = (r == 0) ? ulo(xvp[ntl][0]) : (r == 1) ? uhi(xvp[ntl][0])
               : (r == 2) ? ulo(xvp[ntl][1]) : uhi(xvp[ntl][1]);
      outF[(size_t)(m0 + row_l + r) * 256 + col] = acc[ntl][r] + bv + xr;
    }
  }
#undef ASW
#undef ASR8
#undef STGW
#undef KLOOP
}

extern "C" void kernel_launch(void* const* d_in, const int* in_sizes, int n_in,
                              void* d_out, int out_size, void* d_ws, size_t ws_size,
                              hipStream_t stream)
{
  const float* node_emb = (const float*)d_in[0];
  const float* cluster  = (const float*)d_in[1];
  const float* cw       = (const float*)d_in[2];
  const float* ln_q_g   = (const float*)d_in[3];
  const float* ln_q_b   = (const float*)d_in[4];
  const float* ln_kv_g  = (const float*)d_in[5];
  const float* ln_kv_b  = (const float*)d_in[6];
  const float* ln_o_g   = (const float*)d_in[7];
  const float* ln_o_b   = (const float*)d_in[8];
  const float* W_q  = (const float*)d_in[9];  const float* b_q  = (const float*)d_in[10];
  const float* W_k  = (const float*)d_in[11]; const float* b_k  = (const float*)d_in[12];
  const float* W_v  = (const float*)d_in[13]; const float* b_v  = (const float*)d_in[14];
  const float* W_o  = (const float*)d_in[15]; const float* b_o  = (const float*)d_in[16];
  const float* W_m1 = (const float*)d_in[17]; const float* b_m1 = (const float*)d_in[18];
  const float* W_m2 = (const float*)d_in[19]; const float* b_m2 = (const float*)d_in[20];

  char* ws = (char*)d_ws;
  short* Wst   = (short*)ws;                                   // 786,432 B stage-order (6 slots)
  short* bufA  = (short*)(ws + 786432);                        // 16.78 MB: ctx afrag
  short* bufB  = (short*)(ws + 786432 + 16777216);             // 16.78 MB: Q afrag
  short* kfrag = (short*)(ws + 786432 + 2 * 16777216);
  short* vfrag = (short*)(ws + 786432 + 2 * 16777216 + 1048576);

  float* outF = (float*)d_out;            // final out (written only by tail_k)
  float* amof = (float*)d_out + 8388608;  // attn_matrix

  hipFuncSetAttribute((const void*)attn_k, hipFuncAttributeMaxDynamicSharedMemorySize, 65536);
  hipFuncSetAttribute((const void*)tail_k, hipFuncAttributeMaxDynamicSharedMemorySize, 67584);
  hipFuncSetAttribute((const void*)qkv_k,  hipFuncAttributeMaxDynamicSharedMemorySize, 66560);

  cvt_w<<<1536, 256, 0, stream>>>(W_q, W_k, W_v, W_o, W_m1, W_m2, Wst);
  // fused Q+K+V projections (KV blocks first) -> bufB / kfrag / vfrag
  qkv_k<<<544, 512, 66560, stream>>>(node_emb, cluster, Wst,
      b_q, b_k, b_v, ln_q_g, ln_q_b, ln_kv_g, ln_kv_b, bufB, kfrag, vfrag);
  // attention (ctx afrag -> bufA, attn_matrix -> d_out 2nd half)
  attn_k<<<dim3(64, 8), 256, 65536, stream>>>(bufB, kfrag, vfrag, cw, bufA, amof);
  // fused tail: O(+res)+LN -> M1(+GELU) -> M2(+res) -> out (8-wave blocks)
  tail_k<<<512, 512, 67584, stream>>>(bufA, Wst, b_o, b_m1, b_m2,
      node_emb, ln_o_g, ln_o_b, outF);
}